// Round 21
// baseline (232.699 us; speedup 1.0000x reference)
//
#include <hip/hip_runtime.h>
#include <hip/hip_bf16.h>
#include <stdint.h>

// MoTEmbed: out[t,:] = W_{type(t)} @ h[t,:] + b_{type(t)}
// B=4, S=4096 -> T=16384 tokens, D=2048. fp32 in/out, bf16 MFMA compute.
// Round 21: static-RR-aware packing. 504 regular blocks leave CUs 248-255
// with one block; the straddle tile is split into exactly 8 dual 256x256
// blocks at IDs 504-511 -> they land on those light CUs (R19's 32 small
// pieces forced a third wave on CUs 0-23). Dual path: 256x256, BK=32,
// triple-buffered {A,B0,B1} (144KB), single-barrier 2-phase cadence,
// vmcnt(6) counted drains. Regular path byte-identical to R19.

#define T_TOK 16384
#define DDIM  2048
#define NT_K  32           // K tiles of 64 (regular path)
#define NT_D  64           // K tiles of 32 (dual path)
#define MT    64           // M tiles of 256 (gap-free sort)

typedef __attribute__((ext_vector_type(4))) float          f32x4;
typedef __attribute__((ext_vector_type(8))) short          bf16x8;
typedef __attribute__((ext_vector_type(2))) unsigned int   u32x2;

// ---- ws layout (bytes) ----
#define WS_HBF   0ull
#define WS_W0BF  67108864ull                 // 16384*2048*2
#define WS_W1BF  75497472ull                 // + 2048*2048*2
#define WS_META  83886080ull                 // + 2048*2048*2
#define WS_IDX   83886208ull
#define WS_NEED  (WS_IDX + 65536ull)
// meta: [0]=cur0 (final = c0) [1]=cur1

__device__ __forceinline__ unsigned short cvt1_bf16(float f) {
  unsigned u = __builtin_bit_cast(unsigned, f);
  unsigned rnd = 0x7fffu + ((u >> 16) & 1u);
  return (unsigned short)((u + rnd) >> 16);
}

__device__ __forceinline__ void gload_lds16(const void* g, void* l) {
  __builtin_amdgcn_global_load_lds(
      (const __attribute__((address_space(1))) unsigned int*)g,
      (__attribute__((address_space(3))) unsigned int*)l, 16, 0, 0);
}

#define BAR()     asm volatile("s_barrier" ::: "memory")
#define VMCNT2()  asm volatile("s_waitcnt vmcnt(2)" ::: "memory")
#define VMCNT4()  asm volatile("s_waitcnt vmcnt(4)" ::: "memory")
#define VMCNT6()  asm volatile("s_waitcnt vmcnt(6)" ::: "memory")
#define VMCNT0()  asm volatile("s_waitcnt vmcnt(0)" ::: "memory")
#define LGKM0()   asm volatile("s_waitcnt lgkmcnt(0)" ::: "memory")
#define SCHEDBAR() __builtin_amdgcn_sched_barrier(0)

// ---------- prep: fused convert(H,W0,W1) + two-sided scatter ----------
__global__ void k_prep(const float* __restrict__ H, const float* __restrict__ W0,
                       const float* __restrict__ W1, const int* __restrict__ typ,
                       unsigned short* __restrict__ Hbf,
                       unsigned short* __restrict__ W0bf,
                       unsigned short* __restrict__ W1bf,
                       int* __restrict__ meta, int* __restrict__ idx) {
  const int gid = blockIdx.x * blockDim.x + threadIdx.x;
  if (gid < T_TOK) {
    int t = typ[gid];
    int pos = (t == 0) ? atomicAdd(&meta[0], 1)
                       : (T_TOK - 1) - atomicAdd(&meta[1], 1);
    idx[pos] = gid;
  }
  const int nH = T_TOK * DDIM / 4;
  const int nW = DDIM * DDIM / 4;
  const int total = nH + 2 * nW;
  const int stride = gridDim.x * blockDim.x;
  for (int i = gid; i < total; i += stride) {
    const float* s; unsigned short* d; int j;
    if (i < nH)           { s = H;  d = Hbf;  j = i; }
    else if (i < nH + nW) { s = W0; d = W0bf; j = i - nH; }
    else                  { s = W1; d = W1bf; j = i - nH - nW; }
    f32x4 v = ((const f32x4*)s)[j];
    unsigned p0 = (unsigned)cvt1_bf16(v[0]) | ((unsigned)cvt1_bf16(v[1]) << 16);
    unsigned p1 = (unsigned)cvt1_bf16(v[2]) | ((unsigned)cvt1_bf16(v[3]) << 16);
    u32x2 o; o[0] = p0; o[1] = p1;
    ((u32x2*)d)[j] = o;
  }
}

// ---------- GEMM: 504 regular 256x256 + 8 dual 256x256 (IDs 504-511) ----------
__global__ __launch_bounds__(512) void k_gemm256(
    const unsigned short* __restrict__ Hbf,
    const unsigned short* __restrict__ W0bf,
    const unsigned short* __restrict__ W1bf,
    const float* __restrict__ B0, const float* __restrict__ B1,
    const int* __restrict__ meta, const int* __restrict__ idx,
    float* __restrict__ OUT)
{
  __shared__ char lds[147456];         // regular uses 128K; dual 3x48K

  const int c0 = meta[0];
  int ms = c0 >> 8; if (ms > MT - 1) ms = MT - 1;   // straddle/boundary tile

  const int tid  = threadIdx.x;
  const int lane = tid & 63;
  const int wid  = tid >> 6;           // 0..7
  const int wr   = wid >> 2;           // 0..1 (M half)
  const int wc   = wid & 3;            // 0..3 (N quarter)
  const int fr   = lane & 15;
  const int g    = lane >> 4;
  const int cs   = (lane & 3) ^ ((lane >> 3) & 3);  // pre-swizzled slot
  const int sw   = (g ^ ((fr >> 1) & 3)) << 4;      // read-side swizzle

  // fragment byte offsets within a 256-row x 64B section (swizzled slot)
  int aF[8], bF[4];
#pragma unroll
  for (int m = 0; m < 8; ++m) aF[m] = ((wr * 128 + m * 16 + fr) << 6) + sw;
#pragma unroll
  for (int n = 0; n < 4; ++n) bF[n] = ((wc * 64 + n * 16 + fr) << 6) + sw;

  f32x4 acc[8][4];
#pragma unroll
  for (int m = 0; m < 8; ++m)
#pragma unroll
    for (int n = 0; n < 4; ++n) acc[m][n] = (f32x4)0.0f;

  const int chB = (2 * wid) * 1024;    // wave-uniform chunk base in a section

  if (blockIdx.x < 504) {
    // ================= regular single-expert path (R14/R15 verified) ======
    const int orig = blockIdx.x;
    const int wg = (orig & 7) * 63 + (orig >> 3);
    int i_t = wg >> 3;                 // 0..62
    const int bx = wg & 7;
    const int my = i_t + (i_t >= ms ? 1 : 0);

    const int start = my * 256;
    const int e0 = (start >= c0) ? 1 : 0;
    const int colBase = bx * 256;

    const char* aS[2];
    int rt[2];
#pragma unroll
    for (int l = 0; l < 2; ++l) {
      int ch = 2 * wid + l;
      rt[l] = ch * 16 + (lane >> 2);
      int orow = idx[start + rt[l]];
      aS[l] = (const char*)Hbf + (size_t)orow * 4096 + cs * 16;
    }

    const unsigned short* Wb = e0 ? W1bf : W0bf;
    const char* wS[2];
#pragma unroll
    for (int l = 0; l < 2; ++l)
      wS[l] = (const char*)(Wb + (size_t)(colBase + rt[l]) * DDIM) + cs * 16;

    auto STAGE_A = [&](int d, int kh, int tn) {
      char* dst = lds + (d << 15) + (kh << 14) + chB;
      int ko = tn * 128 + kh * 64;
      gload_lds16(aS[0] + ko, dst);
      gload_lds16(aS[1] + ko, dst + 1024);
    };
    auto STAGE_B = [&](int d, int kh, int tn) {
      char* dst = lds + 65536 + (d << 15) + (kh << 14) + chB;
      int ko = tn * 128 + kh * 64;
      gload_lds16(wS[0] + ko, dst);
      gload_lds16(wS[1] + ko, dst + 1024);
    };

    STAGE_A(0, 0, 0); STAGE_B(0, 0, 0); STAGE_A(0, 1, 0); STAGE_B(0, 1, 0);
    VMCNT4();
    BAR();

#pragma unroll 2
    for (int t = 0; t < NT_K; ++t) {
      const int c = t & 1, d = c ^ 1;
      int t1 = t + 1; if (t1 == NT_K) t1 = NT_K - 1;
      const char* Ak0 = lds + (c << 15);
      const char* Ak1 = Ak0 + 16384;
      const char* Bk0 = lds + 65536 + (c << 15);
      const char* Bk1 = Bk0 + 16384;

      bf16x8 a[8], bb0, bb1;

      // P1: kh0 x n0-1
#pragma unroll
      for (int m = 0; m < 8; ++m) a[m] = *(const bf16x8*)(Ak0 + aF[m]);
      bb0 = *(const bf16x8*)(Bk0 + bF[0]);
      bb1 = *(const bf16x8*)(Bk0 + bF[1]);
      STAGE_A(d, 0, t1);
      BAR(); LGKM0(); SCHEDBAR();
      __builtin_amdgcn_s_setprio(1);
#pragma unroll
      for (int m = 0; m < 8; ++m) {
        acc[m][0] = __builtin_amdgcn_mfma_f32_16x16x32_bf16(a[m], bb0, acc[m][0], 0, 0, 0);
        acc[m][1] = __builtin_amdgcn_mfma_f32_16x16x32_bf16(a[m], bb1, acc[m][1], 0, 0, 0);
      }
      __builtin_amdgcn_s_setprio(0);

      // P2: kh0 x n2-3
      bb0 = *(const bf16x8*)(Bk0 + bF[2]);
      bb1 = *(const bf16x8*)(Bk0 + bF[3]);
      VMCNT2();
      STAGE_B(d, 0, t1);
      BAR(); LGKM0(); SCHEDBAR();
      __builtin_amdgcn_s_setprio(1);
#pragma unroll
      for (int m = 0; m < 8; ++m) {
        acc[m][2] = __builtin_amdgcn_mfma_f32_16x16x32_bf16(a[m], bb0, acc[m][2], 0, 0, 0);
        acc[m][3] = __builtin_amdgcn_mfma_f32_16x16x32_bf16(a[m], bb1, acc[m][3], 0, 0, 0);
      }
      __builtin_amdgcn_s_setprio(0);

      // P3: kh1 x n0-1
#pragma unroll
      for (int m = 0; m < 8; ++m) a[m] = *(const bf16x8*)(Ak1 + aF[m]);
      bb0 = *(const bf16x8*)(Bk1 + bF[0]);
      bb1 = *(const bf16x8*)(Bk1 + bF[1]);
      STAGE_A(d, 1, t1);
      BAR(); LGKM0(); SCHEDBAR();
      __builtin_amdgcn_s_setprio(1);
#pragma unroll
      for (int m = 0; m < 8; ++m) {
        acc[m][0] = __builtin_amdgcn_mfma_f32_16x16x32_bf16(a[m], bb0, acc[m][0], 0, 0, 0);
        acc[m][1] = __builtin_amdgcn_mfma_f32_16x16x32_bf16(a[m], bb1, acc[m][1], 0, 0, 0);
      }
      __builtin_amdgcn_s_setprio(0);

      // P4: kh1 x n2-3
      bb0 = *(const bf16x8*)(Bk1 + bF[2]);
      bb1 = *(const bf16x8*)(Bk1 + bF[3]);
      VMCNT2();
      STAGE_B(d, 1, t1);
      BAR(); LGKM0(); SCHEDBAR();
      __builtin_amdgcn_s_setprio(1);
#pragma unroll
      for (int m = 0; m < 8; ++m) {
        acc[m][2] = __builtin_amdgcn_mfma_f32_16x16x32_bf16(a[m], bb0, acc[m][2], 0, 0, 0);
        acc[m][3] = __builtin_amdgcn_mfma_f32_16x16x32_bf16(a[m], bb1, acc[m][3], 0, 0, 0);
      }
      __builtin_amdgcn_s_setprio(0);
    }

    VMCNT0();

    const float* Bv = e0 ? B1 : B0;
    float bias[4];
    int cols[4];
#pragma unroll
    for (int n = 0; n < 4; ++n) {
      cols[n] = colBase + wc * 64 + n * 16 + fr;
      bias[n] = Bv[cols[n]];
    }
#pragma unroll
    for (int m = 0; m < 8; ++m) {
      int lb = wr * 128 + m * 16 + (g << 2);
#pragma unroll
      for (int j = 0; j < 4; ++j) {
        int orow = idx[start + lb + j];
        float* op = OUT + (size_t)orow * DDIM;
#pragma unroll
        for (int n = 0; n < 4; ++n) op[cols[n]] = acc[m][n][j] + bias[n];
      }
    }
  } else {
    // ====== dual 256x256 boundary tile: BK=32, triple-buffered ============
    // Bufs (48KB each) at lds + b*49152: A 16K | B0 16K @+16384 | B1 @+32768.
    // Tile t (c=t%3, d=(t+2)%3):
    //  P1: read A(c) m0-7 + B(c) n0-1; stage A,B0(d,t+2) [4]; BAR; lgkm0;
    //      MFMA n0-1 (per-m expert select).
    //  P2: read B(c) n2-3; stage B1(d,t+2) [2]; vmcnt(6) retires S(t+1)
    //      (issued 1 tile ~1450cyc earlier); BAR; lgkm0; MFMA n2-3.
    // Census: 6 loads/tile; at P2 drain outstanding = S(t+1)6+S(t+2)6=12.
    // WAR: buf d = (t-1)%3, readers done before P2(t-1) BAR < stage.
    // Visibility: S(t) retired at P2(t-1) vmcnt(6) before its BAR. Never
    // vmcnt(0) in loop.
    const int bx = blockIdx.x - 504;   // 0..7
    const int colBase = bx * 256;
    const int start = ms * 256;

    const char* aS[2];
    int rt[2];
#pragma unroll
    for (int l = 0; l < 2; ++l) {
      int ch = 2 * wid + l;
      rt[l] = ch * 16 + (lane >> 2);
      int orow = idx[start + rt[l]];
      aS[l] = (const char*)Hbf + (size_t)orow * 4096 + cs * 16;
    }
    const char* wS0[2]; const char* wS1[2];
#pragma unroll
    for (int l = 0; l < 2; ++l) {
      wS0[l] = (const char*)(W0bf + (size_t)(colBase + rt[l]) * DDIM) + cs * 16;
      wS1[l] = (const char*)(W1bf + (size_t)(colBase + rt[l]) * DDIM) + cs * 16;
    }

    const int lo_w = c0 - start - wr * 128;      // wave-uniform
    const int pure0 = (lo_w >= 128);             // whole wave expert 0
    const int pure1 = (lo_w <= 0);               // whole wave expert 1
    int mmix = 8;
    if (!pure0 && !pure1 && (lo_w & 15)) mmix = lo_w >> 4;

    f32x4 accX[4];
#pragma unroll
    for (int n = 0; n < 4; ++n) accX[n] = (f32x4)0.0f;

    auto STAGE_AB0 = [&](int d, int tn) {
      char* base = lds + d * 49152;
      int ko = tn * 64;
      gload_lds16(aS[0] + ko, base + chB);
      gload_lds16(aS[1] + ko, base + chB + 1024);
      gload_lds16(wS0[0] + ko, base + 16384 + chB);
      gload_lds16(wS0[1] + ko, base + 16384 + chB + 1024);
    };
    auto STAGE_B1 = [&](int d, int tn) {
      char* base = lds + d * 49152;
      int ko = tn * 64;
      gload_lds16(wS1[0] + ko, base + 32768 + chB);
      gload_lds16(wS1[1] + ko, base + 32768 + chB + 1024);
    };

    // prologue: S0 -> buf0, S1 -> buf1 (6 loads each); retire S0; BAR
    STAGE_AB0(0, 0); STAGE_B1(0, 0);
    STAGE_AB0(1, 1); STAGE_B1(1, 1);
    VMCNT6();
    BAR();

    for (int t = 0; t < NT_D; ++t) {
      const int c = t % 3;
      const int d = (t + 2) % 3;
      int t2 = t + 2; if (t2 >= NT_D) t2 = NT_D - 1;
      const char* Ac  = lds + c * 49152;
      const char* B0c = Ac + 16384;
      const char* B1c = Ac + 32768;
      const char* Bown = pure1 ? B1c : B0c;
      const int mixed = (!pure0 && !pure1);

      bf16x8 a[8], b0a, b0b, b1a, b1b;

      // ---- P1: n0-1 ----
#pragma unroll
      for (int m = 0; m < 8; ++m) a[m] = *(const bf16x8*)(Ac + aF[m]);
      b0a = *(const bf16x8*)(Bown + bF[0]);
      b0b = *(const bf16x8*)(Bown + bF[1]);
      if (mixed) {
        b1a = *(const bf16x8*)(B1c + bF[0]);
        b1b = *(const bf16x8*)(B1c + bF[1]);
      }
      STAGE_AB0(d, t2);
      BAR(); LGKM0(); SCHEDBAR();
      __builtin_amdgcn_s_setprio(1);
      if (!mixed) {
#pragma unroll
        for (int m = 0; m < 8; ++m) {
          acc[m][0] = __builtin_amdgcn_mfma_f32_16x16x32_bf16(a[m], b0a, acc[m][0], 0, 0, 0);
          acc[m][1] = __builtin_amdgcn_mfma_f32_16x16x32_bf16(a[m], b0b, acc[m][1], 0, 0, 0);
        }
      } else {
#pragma unroll
        for (int m = 0; m < 8; ++m) {
          if (m == mmix) {
            acc[m][0] = __builtin_amdgcn_mfma_f32_16x16x32_bf16(a[m], b0a, acc[m][0], 0, 0, 0);
            acc[m][1] = __builtin_amdgcn_mfma_f32_16x16x32_bf16(a[m], b0b, acc[m][1], 0, 0, 0);
            accX[0]   = __builtin_amdgcn_mfma_f32_16x16x32_bf16(a[m], b1a, accX[0],   0, 0, 0);
            accX[1]   = __builtin_amdgcn_mfma_f32_16x16x32_bf16(a[m], b1b, accX[1],   0, 0, 0);
          } else if (m * 16 >= lo_w) {
            acc[m][0] = __builtin_amdgcn_mfma_f32_16x16x32_bf16(a[m], b1a, acc[m][0], 0, 0, 0);
            acc[m][1] = __builtin_amdgcn_mfma_f32_16x16x32_bf16(a[m], b1b, acc[m][1], 0, 0, 0);
          } else {
            acc[m][0] = __builtin_amdgcn_mfma_f32_16x16x32_bf16(a[m], b0a, acc[m][0], 0, 0, 0);
            acc[m][1] = __builtin_amdgcn_mfma_f32_16x16x32_bf16(a[m], b0b, acc[m][1], 0, 0, 0);
          }
        }
      }
      __builtin_amdgcn_s_setprio(0);

      // ---- P2: n2-3 ----
      b0a = *(const bf16x8*)(Bown + bF[2]);
      b0b = *(const bf16x8*)(Bown + bF[3]);
      if (mixed) {
        b1a = *(const bf16x8*)(B1c + bF[2]);
        b1b = *(const bf16x8*)(B1c + bF[3]);
      }
      STAGE_B1(d, t2);
      VMCNT6();                        // retires S(t+1): buf(t+1) certified
      BAR(); LGKM0(); SCHEDBAR();
      __builtin_amdgcn_s_setprio(1);
      if (!mixed) {
#pragma unroll
        for (int m = 0; m < 8; ++m) {
          acc[m][2] = __builtin_amdgcn_mfma_f32_16x16x32_bf16(a[m], b0a, acc[m][2], 0, 0, 0);
          acc[m][3] = __builtin_amdgcn_mfma_f32_16x16x32_bf16(a[m], b0b, acc[m][3], 0, 0, 0);
        }
      } else {
#pragma unroll
        for (int m = 0; m < 8; ++m) {
          if (m == mmix) {
            acc[m][2] = __builtin_amdgcn_mfma_f32_16x16x32_bf16(a[m], b0a, acc[m][2], 0, 0, 0);
            acc[m][3] = __builtin_amdgcn_mfma_f32_16x16x32_bf16(a[m], b0b, acc[m][3], 0, 0, 0);
            accX[2]   = __builtin_amdgcn_mfma_f32_16x16x32_bf16(a[m], b1a, accX[2],   0, 0, 0);
            accX[3]   = __builtin_amdgcn_mfma_f32_16x16x32_bf16(a[m], b1b, accX[3],   0, 0, 0);
          } else if (m * 16 >= lo_w) {
            acc[m][2] = __builtin_amdgcn_mfma_f32_16x16x32_bf16(a[m], b1a, acc[m][2], 0, 0, 0);
            acc[m][3] = __builtin_amdgcn_mfma_f32_16x16x32_bf16(a[m], b1b, acc[m][3], 0, 0, 0);
          } else {
            acc[m][2] = __builtin_amdgcn_mfma_f32_16x16x32_bf16(a[m], b0a, acc[m][2], 0, 0, 0);
            acc[m][3] = __builtin_amdgcn_mfma_f32_16x16x32_bf16(a[m], b0b, acc[m][3], 0, 0, 0);
          }
        }
      }
      __builtin_amdgcn_s_setprio(0);
      BAR();                           // buf c reads done -> next stage WAR-safe
    }
    VMCNT0();

    int cols[4];
    float bias0v[4], bias1v[4];
#pragma unroll
    for (int n = 0; n < 4; ++n) {
      cols[n] = colBase + wc * 64 + n * 16 + fr;
      bias0v[n] = B0[cols[n]];
      bias1v[n] = B1[cols[n]];
    }
#pragma unroll
    for (int m = 0; m < 8; ++m) {
      int lb = wr * 128 + m * 16 + (g << 2);
      if (m == mmix) {
#pragma unroll
        for (int j = 0; j < 4; ++j) {
          int p = start + lb + j;
          int orow = idx[p];
          float* op = OUT + (size_t)orow * DDIM;
          if (p >= c0) {
#pragma unroll
            for (int n = 0; n < 4; ++n) op[cols[n]] = accX[n][j] + bias1v[n];
          } else {
#pragma unroll
            for (int n = 0; n < 4; ++n) op[cols[n]] = acc[m][n][j] + bias0v[n];
          }
        }
      } else {
#pragma unroll
        for (int j = 0; j < 4; ++j) {
          int p = start + lb + j;
          int orow = idx[p];
          float* op = OUT + (size_t)orow * DDIM;
          int e1r = (p >= c0) ? 1 : 0;
#pragma unroll
          for (int n = 0; n < 4; ++n)
            op[cols[n]] = acc[m][n][j] + (e1r ? bias1v[n] : bias0v[n]);
        }
      }
    }
  }
}

// ---------- fallback: verified round-4 kernel ----------
#define BMd 64
#define BNd 64
#define BKd 32
#define LDW 36

__device__ __forceinline__ bf16x8 cvt_bf16x8(f32x4 lo, f32x4 hi) {
  bf16x8 r;
#pragma unroll
  for (int i = 0; i < 4; ++i) {
    r[i]     = (short)cvt1_bf16(lo[i]);
    r[i + 4] = (short)cvt1_bf16(hi[i]);
  }
  return r;
}

__global__ __launch_bounds__(256, 2) void mot_mfma_diag(
    const float* __restrict__ H,  const int* __restrict__ TYP,
    const float* __restrict__ W0, const float* __restrict__ B0,
    const float* __restrict__ W1, const float* __restrict__ B1,
    float* __restrict__ OUT)
{
  __shared__ float As[BMd * LDW];
  __shared__ float W0s[BNd * LDW];
  __shared__ float W1s[BNd * LDW];

  const int tid = threadIdx.x;
  const int rowBase = blockIdx.y * BMd;
  const int colBase = blockIdx.x * BNd;
  const int srow  = tid >> 3;
  const int scol4 = (tid & 7) << 2;
  const float* hA  = H  + (size_t)(rowBase + srow) * DDIM + scol4;
  const float* hW0 = W0 + (size_t)(colBase + srow) * DDIM + scol4;
  const float* hW1 = W1 + (size_t)(colBase + srow) * DDIM + scol4;

  const int lane = tid & 63;
  const int w    = tid >> 6;
  const int fr   = lane & 15;
  const int g    = lane >> 4;

  f32x4 acc0[4], acc1[4];
#pragma unroll
  for (int m = 0; m < 4; ++m) { acc0[m] = (f32x4)0.0f; acc1[m] = (f32x4)0.0f; }

  for (int k0 = 0; k0 < DDIM; k0 += BKd) {
    f32x4 va[2], v0[2], v1[2];
#pragma unroll
    for (int p = 0; p < 2; ++p) {
      va[p] = *(const f32x4*)(hA  + (size_t)p * 32 * DDIM);
      v0[p] = *(const f32x4*)(hW0 + (size_t)p * 32 * DDIM);
      v1[p] = *(const f32x4*)(hW1 + (size_t)p * 32 * DDIM);
    }
    hA += BKd; hW0 += BKd; hW1 += BKd;
    __syncthreads();
#pragma unroll
    for (int p = 0; p < 2; ++p) {
      int r = srow + 32 * p;
      *(f32x4*)(&As [r * LDW + scol4]) = va[p];
      *(f32x4*)(&W0s[r * LDW + scol4]) = v0[p];
      *(f32x4*)(&W1s[r * LDW + scol4]) = v1[p];
    }
    __syncthreads();

    bf16x8 af[4];
#pragma unroll
    for (int m = 0; m < 4; ++m) {
      const float* ap = &As[(m * 16 + fr) * LDW + g * 8];
      af[m] = cvt_bf16x8(*(const f32x4*)ap, *(const f32x4*)(ap + 4));
    }
    const float* b0p = &W0s[(w * 16 + fr) * LDW + g * 8];
    const float* b1p = &W1s[(w * 16 + fr) * LDW + g * 8];
    bf16x8 bf0 = cvt_bf16x8(*(const f32x4*)b0p, *(const f32x4*)(b0p + 4));
    bf16x8 bf1 = cvt_bf16x8(*(const f32x4*)b1p, *(const f32x4*)(b1p + 4));
#pragma unroll
    for (int m = 0; m < 4; ++m) {
      acc0[m] = __builtin_amdgcn_mfma_f32_16x16x32_bf16(af[m], bf0, acc0[m], 0, 0, 0);
      acc1[m] = __builtin_amdgcn_mfma_f32_16x16x32_bf16(af[m], bf1, acc1[m], 0, 0, 0);
    }
  }

  const int col = colBase + w * 16 + fr;
  const float bz0 = B0[col];
  const float bz1 = B1[col];
#pragma unroll
  for (int m = 0; m < 4; ++m)
#pragma unroll
    for (int j = 0; j < 4; ++j) {
      int row = rowBase + m * 16 + (g << 2) + j;
      int t = TYP[row];
      OUT[(size_t)row * DDIM + col] = (t == 0) ? (acc0[m][j] + bz0) : (acc1[m][j] + bz1);
    }
}

extern "C" void kernel_launch(void* const* d_in, const int* in_sizes, int n_in,
                              void* d_out, int out_size, void* d_ws, size_t ws_size,
                              hipStream_t stream) {
  const float* H   = (const float*)d_in[0];
  const int*   TYP = (const int*)  d_in[1];
  const float* W0  = (const float*)d_in[2];
  const float* B0v = (const float*)d_in[3];
  const float* W1  = (const float*)d_in[4];
  const float* B1v = (const float*)d_in[5];
  float* OUT = (float*)d_out;

  if (ws_size < WS_NEED) {
    dim3 grid(DDIM / BNd, T_TOK / BMd);
    mot_mfma_diag<<<grid, dim3(256), 0, stream>>>(H, TYP, W0, B0v, W1, B1v, OUT);
    return;
  }

  unsigned short* Hbf  = (unsigned short*)((char*)d_ws + WS_HBF);
  unsigned short* W0bf = (unsigned short*)((char*)d_ws + WS_W0BF);
  unsigned short* W1bf = (unsigned short*)((char*)d_ws + WS_W1BF);
  int* meta = (int*)((char*)d_ws + WS_META);
  int* idx  = (int*)((char*)d_ws + WS_IDX);

  hipMemsetAsync(meta, 0, 16, stream);
  k_prep<<<4096, 256, 0, stream>>>(H, W0, W1, TYP, Hbf, W0bf, W1bf, meta, idx);
  k_gemm256<<<512, 512, 0, stream>>>(Hbf, W0bf, W1bf, B0v, B1v, meta, idx, OUT);
}

// Round 22
// 200.520 us; speedup vs baseline: 1.1605x; 1.1605x over previous
//
#include <hip/hip_runtime.h>
#include <hip/hip_bf16.h>
#include <stdint.h>

// MoTEmbed: out[t,:] = W_{type(t)} @ h[t,:] + b_{type(t)}
// B=4, S=4096 -> T=16384 tokens, D=2048. fp32 in/out, bf16 MFMA compute.
// Round 22: R19 base (best; R21's 256^2 dual reverted). Straddle tile now
// split into 64 pieces of 128x64 (IDs 504-567): 8 land on light CUs
// 248-255 (2nd wave), 56 are a ~15us third wave on CUs 0-55 (R19's 256x64
// pieces cost ~39us). Regular path / prep byte-identical to R19.

#define T_TOK 16384
#define DDIM  2048
#define NT_K  32           // K tiles of 64 (regular path)
#define NT_D  64           // K tiles of 32 (dual path)
#define MT    64           // M tiles of 256 (gap-free sort)

typedef __attribute__((ext_vector_type(4))) float          f32x4;
typedef __attribute__((ext_vector_type(8))) short          bf16x8;
typedef __attribute__((ext_vector_type(2))) unsigned int   u32x2;

// ---- ws layout (bytes) ----
#define WS_HBF   0ull
#define WS_W0BF  67108864ull                 // 16384*2048*2
#define WS_W1BF  75497472ull                 // + 2048*2048*2
#define WS_META  83886080ull                 // + 2048*2048*2
#define WS_IDX   83886208ull
#define WS_NEED  (WS_IDX + 65536ull)
// meta: [0]=cur0 (final = c0) [1]=cur1

__device__ __forceinline__ unsigned short cvt1_bf16(float f) {
  unsigned u = __builtin_bit_cast(unsigned, f);
  unsigned rnd = 0x7fffu + ((u >> 16) & 1u);
  return (unsigned short)((u + rnd) >> 16);
}

__device__ __forceinline__ void gload_lds16(const void* g, void* l) {
  __builtin_amdgcn_global_load_lds(
      (const __attribute__((address_space(1))) unsigned int*)g,
      (__attribute__((address_space(3))) unsigned int*)l, 16, 0, 0);
}

#define BAR()     asm volatile("s_barrier" ::: "memory")
#define VMCNT2()  asm volatile("s_waitcnt vmcnt(2)" ::: "memory")
#define VMCNT4()  asm volatile("s_waitcnt vmcnt(4)" ::: "memory")
#define VMCNT0()  asm volatile("s_waitcnt vmcnt(0)" ::: "memory")
#define LGKM0()   asm volatile("s_waitcnt lgkmcnt(0)" ::: "memory")
#define SCHEDBAR() __builtin_amdgcn_sched_barrier(0)

// ---------- prep: fused convert(H,W0,W1) + two-sided scatter ----------
__global__ void k_prep(const float* __restrict__ H, const float* __restrict__ W0,
                       const float* __restrict__ W1, const int* __restrict__ typ,
                       unsigned short* __restrict__ Hbf,
                       unsigned short* __restrict__ W0bf,
                       unsigned short* __restrict__ W1bf,
                       int* __restrict__ meta, int* __restrict__ idx) {
  const int gid = blockIdx.x * blockDim.x + threadIdx.x;
  if (gid < T_TOK) {
    int t = typ[gid];
    int pos = (t == 0) ? atomicAdd(&meta[0], 1)
                       : (T_TOK - 1) - atomicAdd(&meta[1], 1);
    idx[pos] = gid;
  }
  const int nH = T_TOK * DDIM / 4;
  const int nW = DDIM * DDIM / 4;
  const int total = nH + 2 * nW;
  const int stride = gridDim.x * blockDim.x;
  for (int i = gid; i < total; i += stride) {
    const float* s; unsigned short* d; int j;
    if (i < nH)           { s = H;  d = Hbf;  j = i; }
    else if (i < nH + nW) { s = W0; d = W0bf; j = i - nH; }
    else                  { s = W1; d = W1bf; j = i - nH - nW; }
    f32x4 v = ((const f32x4*)s)[j];
    unsigned p0 = (unsigned)cvt1_bf16(v[0]) | ((unsigned)cvt1_bf16(v[1]) << 16);
    unsigned p1 = (unsigned)cvt1_bf16(v[2]) | ((unsigned)cvt1_bf16(v[3]) << 16);
    u32x2 o; o[0] = p0; o[1] = p1;
    ((u32x2*)d)[j] = o;
  }
}

// ---------- GEMM: 504 regular 256x256 + 64 tail dual 128x64 ----------
__global__ __launch_bounds__(512) void k_gemm256(
    const unsigned short* __restrict__ Hbf,
    const unsigned short* __restrict__ W0bf,
    const unsigned short* __restrict__ W1bf,
    const float* __restrict__ B0, const float* __restrict__ B1,
    const int* __restrict__ meta, const int* __restrict__ idx,
    float* __restrict__ OUT)
{
  __shared__ char lds[131072];

  const int c0 = meta[0];
  int ms = c0 >> 8; if (ms > MT - 1) ms = MT - 1;   // straddle/boundary tile

  const int tid  = threadIdx.x;
  const int lane = tid & 63;
  const int wid  = tid >> 6;           // 0..7
  const int fr   = lane & 15;
  const int g    = lane >> 4;
  const int cs   = (lane & 3) ^ ((lane >> 3) & 3);  // pre-swizzled slot
  const int sw   = (g ^ ((fr >> 1) & 3)) << 4;      // read-side swizzle

  if (blockIdx.x < 504) {
    // ================= regular single-expert path (R14/R15 verified) ======
    const int orig = blockIdx.x;
    const int wg = (orig & 7) * 63 + (orig >> 3);
    int i_t = wg >> 3;                 // 0..62
    const int bx = wg & 7;
    const int my = i_t + (i_t >= ms ? 1 : 0);

    const int wr = wid >> 2;           // 0..1 (M half)
    const int wc = wid & 3;            // 0..3 (N quarter)
    const int start = my * 256;
    const int e0 = (start >= c0) ? 1 : 0;
    const int colBase = bx * 256;

    const char* aS[2];
    int rt[2];
#pragma unroll
    for (int l = 0; l < 2; ++l) {
      int ch = 2 * wid + l;
      rt[l] = ch * 16 + (lane >> 2);
      int orow = idx[start + rt[l]];
      aS[l] = (const char*)Hbf + (size_t)orow * 4096 + cs * 16;
    }
    const int chB = (2 * wid) * 1024;

    int aF[8], bF[4];
#pragma unroll
    for (int m = 0; m < 8; ++m) aF[m] = ((wr * 128 + m * 16 + fr) << 6) + sw;
#pragma unroll
    for (int n = 0; n < 4; ++n) bF[n] = ((wc * 64 + n * 16 + fr) << 6) + sw;

    f32x4 acc[8][4];
#pragma unroll
    for (int m = 0; m < 8; ++m)
#pragma unroll
      for (int n = 0; n < 4; ++n) acc[m][n] = (f32x4)0.0f;

    const unsigned short* Wb = e0 ? W1bf : W0bf;
    const char* wS[2];
#pragma unroll
    for (int l = 0; l < 2; ++l)
      wS[l] = (const char*)(Wb + (size_t)(colBase + rt[l]) * DDIM) + cs * 16;

    auto STAGE_A = [&](int d, int kh, int tn) {
      char* dst = lds + (d << 15) + (kh << 14) + chB;
      int ko = tn * 128 + kh * 64;
      gload_lds16(aS[0] + ko, dst);
      gload_lds16(aS[1] + ko, dst + 1024);
    };
    auto STAGE_B = [&](int d, int kh, int tn) {
      char* dst = lds + 65536 + (d << 15) + (kh << 14) + chB;
      int ko = tn * 128 + kh * 64;
      gload_lds16(wS[0] + ko, dst);
      gload_lds16(wS[1] + ko, dst + 1024);
    };

    STAGE_A(0, 0, 0); STAGE_B(0, 0, 0); STAGE_A(0, 1, 0); STAGE_B(0, 1, 0);
    VMCNT4();
    BAR();

#pragma unroll 2
    for (int t = 0; t < NT_K; ++t) {
      const int c = t & 1, d = c ^ 1;
      int t1 = t + 1; if (t1 == NT_K) t1 = NT_K - 1;
      const char* Ak0 = lds + (c << 15);
      const char* Ak1 = Ak0 + 16384;
      const char* Bk0 = lds + 65536 + (c << 15);
      const char* Bk1 = Bk0 + 16384;

      bf16x8 a[8], bb0, bb1;

      // P1: kh0 x n0-1
#pragma unroll
      for (int m = 0; m < 8; ++m) a[m] = *(const bf16x8*)(Ak0 + aF[m]);
      bb0 = *(const bf16x8*)(Bk0 + bF[0]);
      bb1 = *(const bf16x8*)(Bk0 + bF[1]);
      STAGE_A(d, 0, t1);
      BAR(); LGKM0(); SCHEDBAR();
      __builtin_amdgcn_s_setprio(1);
#pragma unroll
      for (int m = 0; m < 8; ++m) {
        acc[m][0] = __builtin_amdgcn_mfma_f32_16x16x32_bf16(a[m], bb0, acc[m][0], 0, 0, 0);
        acc[m][1] = __builtin_amdgcn_mfma_f32_16x16x32_bf16(a[m], bb1, acc[m][1], 0, 0, 0);
      }
      __builtin_amdgcn_s_setprio(0);

      // P2: kh0 x n2-3
      bb0 = *(const bf16x8*)(Bk0 + bF[2]);
      bb1 = *(const bf16x8*)(Bk0 + bF[3]);
      VMCNT2();
      STAGE_B(d, 0, t1);
      BAR(); LGKM0(); SCHEDBAR();
      __builtin_amdgcn_s_setprio(1);
#pragma unroll
      for (int m = 0; m < 8; ++m) {
        acc[m][2] = __builtin_amdgcn_mfma_f32_16x16x32_bf16(a[m], bb0, acc[m][2], 0, 0, 0);
        acc[m][3] = __builtin_amdgcn_mfma_f32_16x16x32_bf16(a[m], bb1, acc[m][3], 0, 0, 0);
      }
      __builtin_amdgcn_s_setprio(0);

      // P3: kh1 x n0-1
#pragma unroll
      for (int m = 0; m < 8; ++m) a[m] = *(const bf16x8*)(Ak1 + aF[m]);
      bb0 = *(const bf16x8*)(Bk1 + bF[0]);
      bb1 = *(const bf16x8*)(Bk1 + bF[1]);
      STAGE_A(d, 1, t1);
      BAR(); LGKM0(); SCHEDBAR();
      __builtin_amdgcn_s_setprio(1);
#pragma unroll
      for (int m = 0; m < 8; ++m) {
        acc[m][0] = __builtin_amdgcn_mfma_f32_16x16x32_bf16(a[m], bb0, acc[m][0], 0, 0, 0);
        acc[m][1] = __builtin_amdgcn_mfma_f32_16x16x32_bf16(a[m], bb1, acc[m][1], 0, 0, 0);
      }
      __builtin_amdgcn_s_setprio(0);

      // P4: kh1 x n2-3
      bb0 = *(const bf16x8*)(Bk1 + bF[2]);
      bb1 = *(const bf16x8*)(Bk1 + bF[3]);
      VMCNT2();
      STAGE_B(d, 1, t1);
      BAR(); LGKM0(); SCHEDBAR();
      __builtin_amdgcn_s_setprio(1);
#pragma unroll
      for (int m = 0; m < 8; ++m) {
        acc[m][2] = __builtin_amdgcn_mfma_f32_16x16x32_bf16(a[m], bb0, acc[m][2], 0, 0, 0);
        acc[m][3] = __builtin_amdgcn_mfma_f32_16x16x32_bf16(a[m], bb1, acc[m][3], 0, 0, 0);
      }
      __builtin_amdgcn_s_setprio(0);
    }

    VMCNT0();

    const float* Bv = e0 ? B1 : B0;
    float bias[4];
    int cols[4];
#pragma unroll
    for (int n = 0; n < 4; ++n) {
      cols[n] = colBase + wc * 64 + n * 16 + fr;
      bias[n] = Bv[cols[n]];
    }
#pragma unroll
    for (int m = 0; m < 8; ++m) {
      int lb = wr * 128 + m * 16 + (g << 2);
#pragma unroll
      for (int j = 0; j < 4; ++j) {
        int orow = idx[start + lb + j];
        float* op = OUT + (size_t)orow * DDIM;
#pragma unroll
        for (int n = 0; n < 4; ++n) op[cols[n]] = acc[m][n][j] + bias[n];
      }
    }
  } else {
    // ====== dual boundary tile: 64 pieces of 128x64, BK=32, dbuf =========
    // sub = blockIdx-504 (0..63): mh = sub&1 (M half), nb = sub>>1 (0..31).
    // 8 waves, wave grid 4M x 2N (wave tile 32x32): acc[2][2] + accX[2].
    // LDS per buf (16KB): A 8K (128r) | B0 4K @+8192 | B1 4K @+12288; dbuf.
    // Per tile: DSTAGE(d,t+1) [2 loads/thread: 1 A-chunk + 1 B-chunk];
    // vmcnt(2) drains S(t); BAR; reads (<=6); lgkm0; MFMA; BAR.
    // Census invariant 2 outstanding at entry; never vmcnt(0) in loop.
    const int sub = blockIdx.x - 504;
    const int mh = sub & 1;
    const int nb = sub >> 1;           // 0..31
    const int colBase = nb * 64;
    const int start = ms * 256 + mh * 128;

    const int wr = wid >> 1;           // 0..3 (32-row band)
    const int wc = wid & 1;            // 0..1 (32-col half)

    // A staging: 8 chunks of 16 rows; wave wid stages chunk wid (1 load)
    const char* aS;
    {
      int r_t = wid * 16 + (lane >> 2);
      int orow = idx[start + r_t];
      aS = (const char*)Hbf + (size_t)orow * 4096 + cs * 16;
    }
    // B staging: 4 chunks of 16 rows; waves 0-3 -> B0, 4-7 -> B1 (1 load)
    const unsigned short* Wbs = (wid < 4) ? W0bf : W1bf;
    const int bchunk = wid & 3;
    const char* bS = (const char*)(Wbs + (size_t)(colBase + bchunk * 16 + (lane >> 2)) * DDIM) + cs * 16;

    int aF[2], bF[2];
#pragma unroll
    for (int m = 0; m < 2; ++m) aF[m] = ((wr * 32 + m * 16 + fr) << 6) + sw;
#pragma unroll
    for (int n = 0; n < 2; ++n) bF[n] = ((wc * 32 + n * 16 + fr) << 6) + sw;

    const int lo_w = c0 - start - wr * 32;       // wave-uniform
    const int pure0 = (lo_w >= 32);
    const int pure1 = (lo_w <= 0);
    int mmix = 2;
    if (!pure0 && !pure1 && (lo_w & 15)) mmix = lo_w >> 4;

    f32x4 acc[2][2], accX[2];
#pragma unroll
    for (int m = 0; m < 2; ++m) { acc[m][0] = (f32x4)0.0f; acc[m][1] = (f32x4)0.0f; }
    accX[0] = (f32x4)0.0f; accX[1] = (f32x4)0.0f;

    auto DSTAGE = [&](int d, int tn) {
      int ko = tn * 64;
      char* base = lds + (d << 14);
      gload_lds16(aS + ko, base + wid * 1024);
      gload_lds16(bS + ko, base + 8192 + (wid < 4 ? 0 : 4096) + bchunk * 1024);
    };

    DSTAGE(0, 0);
    VMCNT0();
    BAR();

    for (int t = 0; t < NT_D; ++t) {
      const int c = t & 1, d = c ^ 1;
      int t1 = t + 1; if (t1 == NT_D) t1 = NT_D - 1;
      DSTAGE(d, t1);
      VMCNT2();                        // drains S(t) (no-op at t=0)
      BAR();
      const char* Ac  = lds + (c << 14);
      const char* B0c = Ac + 8192;
      const char* B1c = Ac + 12288;
      const char* Bown = pure1 ? B1c : B0c;
      const int mixed = (!pure0 && !pure1);

      bf16x8 a[2], ba, bb, xa, xb;
#pragma unroll
      for (int m = 0; m < 2; ++m) a[m] = *(const bf16x8*)(Ac + aF[m]);
      ba = *(const bf16x8*)(Bown + bF[0]);
      bb = *(const bf16x8*)(Bown + bF[1]);
      if (mixed) {
        xa = *(const bf16x8*)(B1c + bF[0]);
        xb = *(const bf16x8*)(B1c + bF[1]);
      }
      LGKM0(); SCHEDBAR();
      __builtin_amdgcn_s_setprio(1);
      if (!mixed) {
#pragma unroll
        for (int m = 0; m < 2; ++m) {
          acc[m][0] = __builtin_amdgcn_mfma_f32_16x16x32_bf16(a[m], ba, acc[m][0], 0, 0, 0);
          acc[m][1] = __builtin_amdgcn_mfma_f32_16x16x32_bf16(a[m], bb, acc[m][1], 0, 0, 0);
        }
      } else {
#pragma unroll
        for (int m = 0; m < 2; ++m) {
          if (m == mmix) {
            acc[m][0] = __builtin_amdgcn_mfma_f32_16x16x32_bf16(a[m], ba, acc[m][0], 0, 0, 0);
            acc[m][1] = __builtin_amdgcn_mfma_f32_16x16x32_bf16(a[m], bb, acc[m][1], 0, 0, 0);
            accX[0]   = __builtin_amdgcn_mfma_f32_16x16x32_bf16(a[m], xa, accX[0],   0, 0, 0);
            accX[1]   = __builtin_amdgcn_mfma_f32_16x16x32_bf16(a[m], xb, accX[1],   0, 0, 0);
          } else if (m * 16 >= lo_w) {
            acc[m][0] = __builtin_amdgcn_mfma_f32_16x16x32_bf16(a[m], xa, acc[m][0], 0, 0, 0);
            acc[m][1] = __builtin_amdgcn_mfma_f32_16x16x32_bf16(a[m], xb, acc[m][1], 0, 0, 0);
          } else {
            acc[m][0] = __builtin_amdgcn_mfma_f32_16x16x32_bf16(a[m], ba, acc[m][0], 0, 0, 0);
            acc[m][1] = __builtin_amdgcn_mfma_f32_16x16x32_bf16(a[m], bb, acc[m][1], 0, 0, 0);
          }
        }
      }
      __builtin_amdgcn_s_setprio(0);
      BAR();                           // reads of buf c done -> WAR-safe
    }
    VMCNT0();

    int cols[2];
    float bias0v[2], bias1v[2];
#pragma unroll
    for (int n = 0; n < 2; ++n) {
      cols[n] = colBase + wc * 32 + n * 16 + fr;
      bias0v[n] = B0[cols[n]];
      bias1v[n] = B1[cols[n]];
    }
#pragma unroll
    for (int m = 0; m < 2; ++m) {
#pragma unroll
      for (int j = 0; j < 4; ++j) {
        int p = start + wr * 32 + m * 16 + (g << 2) + j;
        int orow = idx[p];
        float* op = OUT + (size_t)orow * DDIM;
        int e1r = (p >= c0) ? 1 : 0;
        if (m == mmix && e1r) {
#pragma unroll
          for (int n = 0; n < 2; ++n) op[cols[n]] = accX[n][j] + bias1v[n];
        } else {
#pragma unroll
          for (int n = 0; n < 2; ++n)
            op[cols[n]] = acc[m][n][j] + (e1r ? bias1v[n] : bias0v[n]);
        }
      }
    }
  }
}

// ---------- fallback: verified round-4 kernel ----------
#define BMd 64
#define BNd 64
#define BKd 32
#define LDW 36

__device__ __forceinline__ bf16x8 cvt_bf16x8(f32x4 lo, f32x4 hi) {
  bf16x8 r;
#pragma unroll
  for (int i = 0; i < 4; ++i) {
    r[i]     = (short)cvt1_bf16(lo[i]);
    r[i + 4] = (short)cvt1_bf16(hi[i]);
  }
  return r;
}

__global__ __launch_bounds__(256, 2) void mot_mfma_diag(
    const float* __restrict__ H,  const int* __restrict__ TYP,
    const float* __restrict__ W0, const float* __restrict__ B0,
    const float* __restrict__ W1, const float* __restrict__ B1,
    float* __restrict__ OUT)
{
  __shared__ float As[BMd * LDW];
  __shared__ float W0s[BNd * LDW];
  __shared__ float W1s[BNd * LDW];

  const int tid = threadIdx.x;
  const int rowBase = blockIdx.y * BMd;
  const int colBase = blockIdx.x * BNd;
  const int srow  = tid >> 3;
  const int scol4 = (tid & 7) << 2;
  const float* hA  = H  + (size_t)(rowBase + srow) * DDIM + scol4;
  const float* hW0 = W0 + (size_t)(colBase + srow) * DDIM + scol4;
  const float* hW1 = W1 + (size_t)(colBase + srow) * DDIM + scol4;

  const int lane = tid & 63;
  const int w    = tid >> 6;
  const int fr   = lane & 15;
  const int g    = lane >> 4;

  f32x4 acc0[4], acc1[4];
#pragma unroll
  for (int m = 0; m < 4; ++m) { acc0[m] = (f32x4)0.0f; acc1[m] = (f32x4)0.0f; }

  for (int k0 = 0; k0 < DDIM; k0 += BKd) {
    f32x4 va[2], v0[2], v1[2];
#pragma unroll
    for (int p = 0; p < 2; ++p) {
      va[p] = *(const f32x4*)(hA  + (size_t)p * 32 * DDIM);
      v0[p] = *(const f32x4*)(hW0 + (size_t)p * 32 * DDIM);
      v1[p] = *(const f32x4*)(hW1 + (size_t)p * 32 * DDIM);
    }
    hA += BKd; hW0 += BKd; hW1 += BKd;
    __syncthreads();
#pragma unroll
    for (int p = 0; p < 2; ++p) {
      int r = srow + 32 * p;
      *(f32x4*)(&As [r * LDW + scol4]) = va[p];
      *(f32x4*)(&W0s[r * LDW + scol4]) = v0[p];
      *(f32x4*)(&W1s[r * LDW + scol4]) = v1[p];
    }
    __syncthreads();

    bf16x8 af[4];
#pragma unroll
    for (int m = 0; m < 4; ++m) {
      const float* ap = &As[(m * 16 + fr) * LDW + g * 8];
      af[m] = cvt_bf16x8(*(const f32x4*)ap, *(const f32x4*)(ap + 4));
    }
    const float* b0p = &W0s[(w * 16 + fr) * LDW + g * 8];
    const float* b1p = &W1s[(w * 16 + fr) * LDW + g * 8];
    bf16x8 bf0 = cvt_bf16x8(*(const f32x4*)b0p, *(const f32x4*)(b0p + 4));
    bf16x8 bf1 = cvt_bf16x8(*(const f32x4*)b1p, *(const f32x4*)(b1p + 4));
#pragma unroll
    for (int m = 0; m < 4; ++m) {
      acc0[m] = __builtin_amdgcn_mfma_f32_16x16x32_bf16(af[m], bf0, acc0[m], 0, 0, 0);
      acc1[m] = __builtin_amdgcn_mfma_f32_16x16x32_bf16(af[m], bf1, acc1[m], 0, 0, 0);
    }
  }

  const int col = colBase + w * 16 + fr;
  const float bz0 = B0[col];
  const float bz1 = B1[col];
#pragma unroll
  for (int m = 0; m < 4; ++m)
#pragma unroll
    for (int j = 0; j < 4; ++j) {
      int row = rowBase + m * 16 + (g << 2) + j;
      int t = TYP[row];
      OUT[(size_t)row * DDIM + col] = (t == 0) ? (acc0[m][j] + bz0) : (acc1[m][j] + bz1);
    }
}

extern "C" void kernel_launch(void* const* d_in, const int* in_sizes, int n_in,
                              void* d_out, int out_size, void* d_ws, size_t ws_size,
                              hipStream_t stream) {
  const float* H   = (const float*)d_in[0];
  const int*   TYP = (const int*)  d_in[1];
  const float* W0  = (const float*)d_in[2];
  const float* B0v = (const float*)d_in[3];
  const float* W1  = (const float*)d_in[4];
  const float* B1v = (const float*)d_in[5];
  float* OUT = (float*)d_out;

  if (ws_size < WS_NEED) {
    dim3 grid(DDIM / BNd, T_TOK / BMd);
    mot_mfma_diag<<<grid, dim3(256), 0, stream>>>(H, TYP, W0, B0v, W1, B1v, OUT);
    return;
  }

  unsigned short* Hbf  = (unsigned short*)((char*)d_ws + WS_HBF);
  unsigned short* W0bf = (unsigned short*)((char*)d_ws + WS_W0BF);
  unsigned short* W1bf = (unsigned short*)((char*)d_ws + WS_W1BF);
  int* meta = (int*)((char*)d_ws + WS_META);
  int* idx  = (int*)((char*)d_ws + WS_IDX);

  hipMemsetAsync(meta, 0, 16, stream);
  k_prep<<<4096, 256, 0, stream>>>(H, W0, W1, TYP, Hbf, W0bf, W1bf, meta, idx);
  k_gemm256<<<568, 512, 0, stream>>>(Hbf, W0bf, W1bf, B0v, B1v, meta, idx, OUT);
}

// Round 23
// 193.728 us; speedup vs baseline: 1.2012x; 1.0351x over previous
//
#include <hip/hip_runtime.h>
#include <hip/hip_bf16.h>
#include <stdint.h>

// MoTEmbed: out[t,:] = W_{type(t)} @ h[t,:] + b_{type(t)}
// B=4, S=4096 -> T=16384 tokens, D=2048. fp32 in/out, bf16 MFMA compute.
// Round 23: R22 base; dual 128x64 pieces go BK=64 (32 tiles instead of 64:
// the piece is sync-envelope-bound, ~470cyc/tile fixed cost). 4 loads/
// thread/tile, vmcnt(4) counted drains (R22's verified census pattern x2).
// Regular path / prep / sort byte-identical to R22.

#define T_TOK 16384
#define DDIM  2048
#define NT_K  32           // K tiles of 64 (regular path)
#define NT_D2 32           // K tiles of 64 (dual path)
#define MT    64           // M tiles of 256 (gap-free sort)

typedef __attribute__((ext_vector_type(4))) float          f32x4;
typedef __attribute__((ext_vector_type(8))) short          bf16x8;
typedef __attribute__((ext_vector_type(2))) unsigned int   u32x2;

// ---- ws layout (bytes) ----
#define WS_HBF   0ull
#define WS_W0BF  67108864ull                 // 16384*2048*2
#define WS_W1BF  75497472ull                 // + 2048*2048*2
#define WS_META  83886080ull                 // + 2048*2048*2
#define WS_IDX   83886208ull
#define WS_NEED  (WS_IDX + 65536ull)
// meta: [0]=cur0 (final = c0) [1]=cur1

__device__ __forceinline__ unsigned short cvt1_bf16(float f) {
  unsigned u = __builtin_bit_cast(unsigned, f);
  unsigned rnd = 0x7fffu + ((u >> 16) & 1u);
  return (unsigned short)((u + rnd) >> 16);
}

__device__ __forceinline__ void gload_lds16(const void* g, void* l) {
  __builtin_amdgcn_global_load_lds(
      (const __attribute__((address_space(1))) unsigned int*)g,
      (__attribute__((address_space(3))) unsigned int*)l, 16, 0, 0);
}

#define BAR()     asm volatile("s_barrier" ::: "memory")
#define VMCNT2()  asm volatile("s_waitcnt vmcnt(2)" ::: "memory")
#define VMCNT4()  asm volatile("s_waitcnt vmcnt(4)" ::: "memory")
#define VMCNT0()  asm volatile("s_waitcnt vmcnt(0)" ::: "memory")
#define LGKM0()   asm volatile("s_waitcnt lgkmcnt(0)" ::: "memory")
#define SCHEDBAR() __builtin_amdgcn_sched_barrier(0)

// ---------- prep: fused convert(H,W0,W1) + two-sided scatter ----------
__global__ void k_prep(const float* __restrict__ H, const float* __restrict__ W0,
                       const float* __restrict__ W1, const int* __restrict__ typ,
                       unsigned short* __restrict__ Hbf,
                       unsigned short* __restrict__ W0bf,
                       unsigned short* __restrict__ W1bf,
                       int* __restrict__ meta, int* __restrict__ idx) {
  const int gid = blockIdx.x * blockDim.x + threadIdx.x;
  if (gid < T_TOK) {
    int t = typ[gid];
    int pos = (t == 0) ? atomicAdd(&meta[0], 1)
                       : (T_TOK - 1) - atomicAdd(&meta[1], 1);
    idx[pos] = gid;
  }
  const int nH = T_TOK * DDIM / 4;
  const int nW = DDIM * DDIM / 4;
  const int total = nH + 2 * nW;
  const int stride = gridDim.x * blockDim.x;
  for (int i = gid; i < total; i += stride) {
    const float* s; unsigned short* d; int j;
    if (i < nH)           { s = H;  d = Hbf;  j = i; }
    else if (i < nH + nW) { s = W0; d = W0bf; j = i - nH; }
    else                  { s = W1; d = W1bf; j = i - nH - nW; }
    f32x4 v = ((const f32x4*)s)[j];
    unsigned p0 = (unsigned)cvt1_bf16(v[0]) | ((unsigned)cvt1_bf16(v[1]) << 16);
    unsigned p1 = (unsigned)cvt1_bf16(v[2]) | ((unsigned)cvt1_bf16(v[3]) << 16);
    u32x2 o; o[0] = p0; o[1] = p1;
    ((u32x2*)d)[j] = o;
  }
}

// ---------- GEMM: 504 regular 256x256 + 64 tail dual 128x64 (BK=64) ----------
__global__ __launch_bounds__(512) void k_gemm256(
    const unsigned short* __restrict__ Hbf,
    const unsigned short* __restrict__ W0bf,
    const unsigned short* __restrict__ W1bf,
    const float* __restrict__ B0, const float* __restrict__ B1,
    const int* __restrict__ meta, const int* __restrict__ idx,
    float* __restrict__ OUT)
{
  __shared__ char lds[131072];

  const int c0 = meta[0];
  int ms = c0 >> 8; if (ms > MT - 1) ms = MT - 1;   // straddle/boundary tile

  const int tid  = threadIdx.x;
  const int lane = tid & 63;
  const int wid  = tid >> 6;           // 0..7
  const int fr   = lane & 15;
  const int g    = lane >> 4;
  const int cs   = (lane & 3) ^ ((lane >> 3) & 3);  // pre-swizzled slot
  const int sw   = (g ^ ((fr >> 1) & 3)) << 4;      // read-side swizzle

  if (blockIdx.x < 504) {
    // ================= regular single-expert path (R14/R15 verified) ======
    const int orig = blockIdx.x;
    const int wg = (orig & 7) * 63 + (orig >> 3);
    int i_t = wg >> 3;                 // 0..62
    const int bx = wg & 7;
    const int my = i_t + (i_t >= ms ? 1 : 0);

    const int wr = wid >> 2;           // 0..1 (M half)
    const int wc = wid & 3;            // 0..3 (N quarter)
    const int start = my * 256;
    const int e0 = (start >= c0) ? 1 : 0;
    const int colBase = bx * 256;

    const char* aS[2];
    int rt[2];
#pragma unroll
    for (int l = 0; l < 2; ++l) {
      int ch = 2 * wid + l;
      rt[l] = ch * 16 + (lane >> 2);
      int orow = idx[start + rt[l]];
      aS[l] = (const char*)Hbf + (size_t)orow * 4096 + cs * 16;
    }
    const int chB = (2 * wid) * 1024;

    int aF[8], bF[4];
#pragma unroll
    for (int m = 0; m < 8; ++m) aF[m] = ((wr * 128 + m * 16 + fr) << 6) + sw;
#pragma unroll
    for (int n = 0; n < 4; ++n) bF[n] = ((wc * 64 + n * 16 + fr) << 6) + sw;

    f32x4 acc[8][4];
#pragma unroll
    for (int m = 0; m < 8; ++m)
#pragma unroll
      for (int n = 0; n < 4; ++n) acc[m][n] = (f32x4)0.0f;

    const unsigned short* Wb = e0 ? W1bf : W0bf;
    const char* wS[2];
#pragma unroll
    for (int l = 0; l < 2; ++l)
      wS[l] = (const char*)(Wb + (size_t)(colBase + rt[l]) * DDIM) + cs * 16;

    auto STAGE_A = [&](int d, int kh, int tn) {
      char* dst = lds + (d << 15) + (kh << 14) + chB;
      int ko = tn * 128 + kh * 64;
      gload_lds16(aS[0] + ko, dst);
      gload_lds16(aS[1] + ko, dst + 1024);
    };
    auto STAGE_B = [&](int d, int kh, int tn) {
      char* dst = lds + 65536 + (d << 15) + (kh << 14) + chB;
      int ko = tn * 128 + kh * 64;
      gload_lds16(wS[0] + ko, dst);
      gload_lds16(wS[1] + ko, dst + 1024);
    };

    STAGE_A(0, 0, 0); STAGE_B(0, 0, 0); STAGE_A(0, 1, 0); STAGE_B(0, 1, 0);
    VMCNT4();
    BAR();

#pragma unroll 2
    for (int t = 0; t < NT_K; ++t) {
      const int c = t & 1, d = c ^ 1;
      int t1 = t + 1; if (t1 == NT_K) t1 = NT_K - 1;
      const char* Ak0 = lds + (c << 15);
      const char* Ak1 = Ak0 + 16384;
      const char* Bk0 = lds + 65536 + (c << 15);
      const char* Bk1 = Bk0 + 16384;

      bf16x8 a[8], bb0, bb1;

      // P1: kh0 x n0-1
#pragma unroll
      for (int m = 0; m < 8; ++m) a[m] = *(const bf16x8*)(Ak0 + aF[m]);
      bb0 = *(const bf16x8*)(Bk0 + bF[0]);
      bb1 = *(const bf16x8*)(Bk0 + bF[1]);
      STAGE_A(d, 0, t1);
      BAR(); LGKM0(); SCHEDBAR();
      __builtin_amdgcn_s_setprio(1);
#pragma unroll
      for (int m = 0; m < 8; ++m) {
        acc[m][0] = __builtin_amdgcn_mfma_f32_16x16x32_bf16(a[m], bb0, acc[m][0], 0, 0, 0);
        acc[m][1] = __builtin_amdgcn_mfma_f32_16x16x32_bf16(a[m], bb1, acc[m][1], 0, 0, 0);
      }
      __builtin_amdgcn_s_setprio(0);

      // P2: kh0 x n2-3
      bb0 = *(const bf16x8*)(Bk0 + bF[2]);
      bb1 = *(const bf16x8*)(Bk0 + bF[3]);
      VMCNT2();
      STAGE_B(d, 0, t1);
      BAR(); LGKM0(); SCHEDBAR();
      __builtin_amdgcn_s_setprio(1);
#pragma unroll
      for (int m = 0; m < 8; ++m) {
        acc[m][2] = __builtin_amdgcn_mfma_f32_16x16x32_bf16(a[m], bb0, acc[m][2], 0, 0, 0);
        acc[m][3] = __builtin_amdgcn_mfma_f32_16x16x32_bf16(a[m], bb1, acc[m][3], 0, 0, 0);
      }
      __builtin_amdgcn_s_setprio(0);

      // P3: kh1 x n0-1
#pragma unroll
      for (int m = 0; m < 8; ++m) a[m] = *(const bf16x8*)(Ak1 + aF[m]);
      bb0 = *(const bf16x8*)(Bk1 + bF[0]);
      bb1 = *(const bf16x8*)(Bk1 + bF[1]);
      STAGE_A(d, 1, t1);
      BAR(); LGKM0(); SCHEDBAR();
      __builtin_amdgcn_s_setprio(1);
#pragma unroll
      for (int m = 0; m < 8; ++m) {
        acc[m][0] = __builtin_amdgcn_mfma_f32_16x16x32_bf16(a[m], bb0, acc[m][0], 0, 0, 0);
        acc[m][1] = __builtin_amdgcn_mfma_f32_16x16x32_bf16(a[m], bb1, acc[m][1], 0, 0, 0);
      }
      __builtin_amdgcn_s_setprio(0);

      // P4: kh1 x n2-3
      bb0 = *(const bf16x8*)(Bk1 + bF[2]);
      bb1 = *(const bf16x8*)(Bk1 + bF[3]);
      VMCNT2();
      STAGE_B(d, 1, t1);
      BAR(); LGKM0(); SCHEDBAR();
      __builtin_amdgcn_s_setprio(1);
#pragma unroll
      for (int m = 0; m < 8; ++m) {
        acc[m][2] = __builtin_amdgcn_mfma_f32_16x16x32_bf16(a[m], bb0, acc[m][2], 0, 0, 0);
        acc[m][3] = __builtin_amdgcn_mfma_f32_16x16x32_bf16(a[m], bb1, acc[m][3], 0, 0, 0);
      }
      __builtin_amdgcn_s_setprio(0);
    }

    VMCNT0();

    const float* Bv = e0 ? B1 : B0;
    float bias[4];
    int cols[4];
#pragma unroll
    for (int n = 0; n < 4; ++n) {
      cols[n] = colBase + wc * 64 + n * 16 + fr;
      bias[n] = Bv[cols[n]];
    }
#pragma unroll
    for (int m = 0; m < 8; ++m) {
      int lb = wr * 128 + m * 16 + (g << 2);
#pragma unroll
      for (int j = 0; j < 4; ++j) {
        int orow = idx[start + lb + j];
        float* op = OUT + (size_t)orow * DDIM;
#pragma unroll
        for (int n = 0; n < 4; ++n) op[cols[n]] = acc[m][n][j] + bias[n];
      }
    }
  } else {
    // ====== dual boundary tile: 64 pieces of 128x64, BK=64, dbuf ==========
    // sub = blockIdx-504: mh = sub&1, nb = sub>>1 -> colBase = nb*64.
    // 8 waves, wave grid 4M x 2N (wave tile 32x32): acc[2][2] + accX[2].
    // Buf (32KB) at lds + d*32768: A kh0 8K | A kh1 @+8192 | B0 kh0 @+16384 |
    // B0 kh1 @+20480 | B1 kh0 @+24576 | B1 kh1 @+28672.
    // Per tile: DSTAGE(d,t+1) [4 loads]; vmcnt(4) drains S(t); BAR;
    // reads (8-12); lgkm0; MFMA (8-12); BAR.  Entry invariant: outstanding
    // = S(t) = 4; never vmcnt(0) in loop. WAR: buf d readers done before
    // t-1's end-BAR < DSTAGE.
    const int sub = blockIdx.x - 504;
    const int mh = sub & 1;
    const int nb = sub >> 1;           // 0..31
    const int colBase = nb * 64;
    const int start = ms * 256 + mh * 128;

    const int wr = wid >> 1;           // 0..3 (32-row band)
    const int wc = wid & 1;            // 0..1 (32-col half)

    // A staging: per kh-section 8 chunks of 16 rows; wave stages chunk wid
    const char* aS;
    {
      int r_t = wid * 16 + (lane >> 2);
      int orow = idx[start + r_t];
      aS = (const char*)Hbf + (size_t)orow * 4096 + cs * 16;
    }
    // B staging: per kh 4 chunks; waves 0-3 -> B0, 4-7 -> B1
    const unsigned short* Wbs = (wid < 4) ? W0bf : W1bf;
    const int bchunk = wid & 3;
    const char* bS = (const char*)(Wbs + (size_t)(colBase + bchunk * 16 + (lane >> 2)) * DDIM) + cs * 16;
    const int bOfs = (wid < 4) ? 16384 : 24576;

    int aF[2], bF[2];
#pragma unroll
    for (int m = 0; m < 2; ++m) aF[m] = ((wr * 32 + m * 16 + fr) << 6) + sw;
#pragma unroll
    for (int n = 0; n < 2; ++n) bF[n] = ((wc * 32 + n * 16 + fr) << 6) + sw;

    const int lo_w = c0 - start - wr * 32;       // wave-uniform
    const int pure0 = (lo_w >= 32);
    const int pure1 = (lo_w <= 0);
    int mmix = 2;
    if (!pure0 && !pure1 && (lo_w & 15)) mmix = lo_w >> 4;
    const int mixed = (!pure0 && !pure1);

    f32x4 acc[2][2], accX[2];
#pragma unroll
    for (int m = 0; m < 2; ++m) { acc[m][0] = (f32x4)0.0f; acc[m][1] = (f32x4)0.0f; }
    accX[0] = (f32x4)0.0f; accX[1] = (f32x4)0.0f;

    auto DSTAGE = [&](int d, int tn) {
      int ko = tn * 128;
      char* base = lds + (d << 15);
      gload_lds16(aS + ko,      base + wid * 1024);
      gload_lds16(aS + ko + 64, base + 8192 + wid * 1024);
      gload_lds16(bS + ko,      base + bOfs + bchunk * 1024);
      gload_lds16(bS + ko + 64, base + bOfs + 4096 + bchunk * 1024);
    };

    DSTAGE(0, 0);
    VMCNT0();
    BAR();

    for (int t = 0; t < NT_D2; ++t) {
      const int c = t & 1, d = c ^ 1;
      int t1 = t + 1; if (t1 == NT_D2) t1 = NT_D2 - 1;
      DSTAGE(d, t1);
      VMCNT4();                        // drains S(t)
      BAR();
      const char* base = lds + (c << 15);
      const char* A0 = base;
      const char* A1 = base + 8192;
      const char* Bown = base + (pure1 ? 24576 : 16384);
      const char* Bmix = base + 24576;

      bf16x8 a0[2], a1[2], b0[2], b1[2], x0[2], x1[2];
#pragma unroll
      for (int m = 0; m < 2; ++m) {
        a0[m] = *(const bf16x8*)(A0 + aF[m]);
        a1[m] = *(const bf16x8*)(A1 + aF[m]);
      }
#pragma unroll
      for (int n = 0; n < 2; ++n) {
        b0[n] = *(const bf16x8*)(Bown + bF[n]);
        b1[n] = *(const bf16x8*)(Bown + 4096 + bF[n]);
      }
      if (mixed) {
#pragma unroll
        for (int n = 0; n < 2; ++n) {
          x0[n] = *(const bf16x8*)(Bmix + bF[n]);
          x1[n] = *(const bf16x8*)(Bmix + 4096 + bF[n]);
        }
      }
      LGKM0(); SCHEDBAR();
      __builtin_amdgcn_s_setprio(1);
      if (!mixed) {
#pragma unroll
        for (int m = 0; m < 2; ++m)
#pragma unroll
          for (int n = 0; n < 2; ++n) {
            acc[m][n] = __builtin_amdgcn_mfma_f32_16x16x32_bf16(a0[m], b0[n], acc[m][n], 0, 0, 0);
            acc[m][n] = __builtin_amdgcn_mfma_f32_16x16x32_bf16(a1[m], b1[n], acc[m][n], 0, 0, 0);
          }
      } else {
#pragma unroll
        for (int m = 0; m < 2; ++m) {
          if (m == mmix) {
#pragma unroll
            for (int n = 0; n < 2; ++n) {
              acc[m][n] = __builtin_amdgcn_mfma_f32_16x16x32_bf16(a0[m], b0[n], acc[m][n], 0, 0, 0);
              acc[m][n] = __builtin_amdgcn_mfma_f32_16x16x32_bf16(a1[m], b1[n], acc[m][n], 0, 0, 0);
              accX[n]   = __builtin_amdgcn_mfma_f32_16x16x32_bf16(a0[m], x0[n], accX[n],   0, 0, 0);
              accX[n]   = __builtin_amdgcn_mfma_f32_16x16x32_bf16(a1[m], x1[n], accX[n],   0, 0, 0);
            }
          } else if (m * 16 >= lo_w) {
#pragma unroll
            for (int n = 0; n < 2; ++n) {
              acc[m][n] = __builtin_amdgcn_mfma_f32_16x16x32_bf16(a0[m], x0[n], acc[m][n], 0, 0, 0);
              acc[m][n] = __builtin_amdgcn_mfma_f32_16x16x32_bf16(a1[m], x1[n], acc[m][n], 0, 0, 0);
            }
          } else {
#pragma unroll
            for (int n = 0; n < 2; ++n) {
              acc[m][n] = __builtin_amdgcn_mfma_f32_16x16x32_bf16(a0[m], b0[n], acc[m][n], 0, 0, 0);
              acc[m][n] = __builtin_amdgcn_mfma_f32_16x16x32_bf16(a1[m], b1[n], acc[m][n], 0, 0, 0);
            }
          }
        }
      }
      __builtin_amdgcn_s_setprio(0);
      BAR();                           // reads of buf c done -> WAR-safe
    }
    VMCNT0();

    int cols[2];
    float bias0v[2], bias1v[2];
#pragma unroll
    for (int n = 0; n < 2; ++n) {
      cols[n] = colBase + wc * 32 + n * 16 + fr;
      bias0v[n] = B0[cols[n]];
      bias1v[n] = B1[cols[n]];
    }
#pragma unroll
    for (int m = 0; m < 2; ++m) {
#pragma unroll
      for (int j = 0; j < 4; ++j) {
        int p = start + wr * 32 + m * 16 + (g << 2) + j;
        int orow = idx[p];
        float* op = OUT + (size_t)orow * DDIM;
        int e1r = (p >= c0) ? 1 : 0;
        if (m == mmix && e1r) {
#pragma unroll
          for (int n = 0; n < 2; ++n) op[cols[n]] = accX[n][j] + bias1v[n];
        } else {
#pragma unroll
          for (int n = 0; n < 2; ++n)
            op[cols[n]] = acc[m][n][j] + (e1r ? bias1v[n] : bias0v[n]);
        }
      }
    }
  }
}

// ---------- fallback: verified round-4 kernel ----------
#define BMd 64
#define BNd 64
#define BKd 32
#define LDW 36

__device__ __forceinline__ bf16x8 cvt_bf16x8(f32x4 lo, f32x4 hi) {
  bf16x8 r;
#pragma unroll
  for (int i = 0; i < 4; ++i) {
    r[i]     = (short)cvt1_bf16(lo[i]);
    r[i + 4] = (short)cvt1_bf16(hi[i]);
  }
  return r;
}

__global__ __launch_bounds__(256, 2) void mot_mfma_diag(
    const float* __restrict__ H,  const int* __restrict__ TYP,
    const float* __restrict__ W0, const float* __restrict__ B0,
    const float* __restrict__ W1, const float* __restrict__ B1,
    float* __restrict__ OUT)
{
  __shared__ float As[BMd * LDW];
  __shared__ float W0s[BNd * LDW];
  __shared__ float W1s[BNd * LDW];

  const int tid = threadIdx.x;
  const int rowBase = blockIdx.y * BMd;
  const int colBase = blockIdx.x * BNd;
  const int srow  = tid >> 3;
  const int scol4 = (tid & 7) << 2;
  const float* hA  = H  + (size_t)(rowBase + srow) * DDIM + scol4;
  const float* hW0 = W0 + (size_t)(colBase + srow) * DDIM + scol4;
  const float* hW1 = W1 + (size_t)(colBase + srow) * DDIM + scol4;

  const int lane = tid & 63;
  const int w    = tid >> 6;
  const int fr   = lane & 15;
  const int g    = lane >> 4;

  f32x4 acc0[4], acc1[4];
#pragma unroll
  for (int m = 0; m < 4; ++m) { acc0[m] = (f32x4)0.0f; acc1[m] = (f32x4)0.0f; }

  for (int k0 = 0; k0 < DDIM; k0 += BKd) {
    f32x4 va[2], v0[2], v1[2];
#pragma unroll
    for (int p = 0; p < 2; ++p) {
      va[p] = *(const f32x4*)(hA  + (size_t)p * 32 * DDIM);
      v0[p] = *(const f32x4*)(hW0 + (size_t)p * 32 * DDIM);
      v1[p] = *(const f32x4*)(hW1 + (size_t)p * 32 * DDIM);
    }
    hA += BKd; hW0 += BKd; hW1 += BKd;
    __syncthreads();
#pragma unroll
    for (int p = 0; p < 2; ++p) {
      int r = srow + 32 * p;
      *(f32x4*)(&As [r * LDW + scol4]) = va[p];
      *(f32x4*)(&W0s[r * LDW + scol4]) = v0[p];
      *(f32x4*)(&W1s[r * LDW + scol4]) = v1[p];
    }
    __syncthreads();

    bf16x8 af[4];
#pragma unroll
    for (int m = 0; m < 4; ++m) {
      const float* ap = &As[(m * 16 + fr) * LDW + g * 8];
      af[m] = cvt_bf16x8(*(const f32x4*)ap, *(const f32x4*)(ap + 4));
    }
    const float* b0p = &W0s[(w * 16 + fr) * LDW + g * 8];
    const float* b1p = &W1s[(w * 16 + fr) * LDW + g * 8];
    bf16x8 bf0 = cvt_bf16x8(*(const f32x4*)b0p, *(const f32x4*)(b0p + 4));
    bf16x8 bf1 = cvt_bf16x8(*(const f32x4*)b1p, *(const f32x4*)(b1p + 4));
#pragma unroll
    for (int m = 0; m < 4; ++m) {
      acc0[m] = __builtin_amdgcn_mfma_f32_16x16x32_bf16(af[m], bf0, acc0[m], 0, 0, 0);
      acc1[m] = __builtin_amdgcn_mfma_f32_16x16x32_bf16(af[m], bf1, acc1[m], 0, 0, 0);
    }
  }

  const int col = colBase + w * 16 + fr;
  const float bz0 = B0[col];
  const float bz1 = B1[col];
#pragma unroll
  for (int m = 0; m < 4; ++m)
#pragma unroll
    for (int j = 0; j < 4; ++j) {
      int row = rowBase + m * 16 + (g << 2) + j;
      int t = TYP[row];
      OUT[(size_t)row * DDIM + col] = (t == 0) ? (acc0[m][j] + bz0) : (acc1[m][j] + bz1);
    }
}

extern "C" void kernel_launch(void* const* d_in, const int* in_sizes, int n_in,
                              void* d_out, int out_size, void* d_ws, size_t ws_size,
                              hipStream_t stream) {
  const float* H   = (const float*)d_in[0];
  const int*   TYP = (const int*)  d_in[1];
  const float* W0  = (const float*)d_in[2];
  const float* B0v = (const float*)d_in[3];
  const float* W1  = (const float*)d_in[4];
  const float* B1v = (const float*)d_in[5];
  float* OUT = (float*)d_out;

  if (ws_size < WS_NEED) {
    dim3 grid(DDIM / BNd, T_TOK / BMd);
    mot_mfma_diag<<<grid, dim3(256), 0, stream>>>(H, TYP, W0, B0v, W1, B1v, OUT);
    return;
  }

  unsigned short* Hbf  = (unsigned short*)((char*)d_ws + WS_HBF);
  unsigned short* W0bf = (unsigned short*)((char*)d_ws + WS_W0BF);
  unsigned short* W1bf = (unsigned short*)((char*)d_ws + WS_W1BF);
  int* meta = (int*)((char*)d_ws + WS_META);
  int* idx  = (int*)((char*)d_ws + WS_IDX);

  hipMemsetAsync(meta, 0, 16, stream);
  k_prep<<<4096, 256, 0, stream>>>(H, W0, W1, TYP, Hbf, W0bf, W1bf, meta, idx);
  k_gemm256<<<568, 512, 0, stream>>>(Hbf, W0bf, W1bf, B0v, B1v, meta, idx, OUT);
}